// Round 5
// baseline (41265.713 us; speedup 1.0000x reference)
//
#include <hip/hip_runtime.h>
#include <math.h>
#include <stdint.h>

// BiLSTMModel: char-LSTM (GEMM-shaped) -> 2x BiLSTM scans (latency-bound) -> FCs.
// Scan v5: one WAVE per WG (64 thr), 2 hidden units/WG, 256 WGs/dir, grid 512.
// No LDS, no barriers. Each lane polls a disjoint 64B ring slice via EIGHT
// relaxed agent-scope b64 atomic loads (compiler batches under one waitcnt),
// with s_sleep backoff between failed rounds (fabric-contention control).
// 2-slot ring provably safe: every WG consumes every word each step.

#define NPOS 4096
#define GDIM 2048   // 4*H

__device__ __forceinline__ float sigf(float x) { return 1.0f / (1.0f + __expf(-x)); }
__device__ __forceinline__ float tanh_fast(float x) {
  float e = __expf(2.f * x);
  return 1.f - 2.f / (e + 1.f);   // exact at +-inf, NaN-free
}

// ---------------- build transposed concat char weight: Wt[k][g]
__global__ __launch_bounds__(256) void build_wt_kernel(
    const float* __restrict__ cWih, const float* __restrict__ cWhh,
    float* __restrict__ Wt)
{
  __shared__ float tile[64][65];
  const int k0 = blockIdx.x * 64;
  const int g0 = blockIdx.y * 64;
  const float* src = (k0 < 256) ? cWih : cWhh;
  const int sk0 = k0 & 255;
  for (int i = threadIdx.x; i < 64 * 64; i += 256) {
    int r = i >> 6, cc = i & 63;
    tile[r][cc] = src[(size_t)(g0 + r) * 256 + sk0 + cc];
  }
  __syncthreads();
  for (int i = threadIdx.x; i < 64 * 64; i += 256) {
    int kk = i >> 6, gg = i & 63;
    Wt[(size_t)(k0 + kk) * 1024 + g0 + gg] = tile[gg][kk];
  }
}

// ---------------- char LSTM: 256 blocks x 16 words, thread = channel
__global__ __launch_bounds__(256) void char_lstm_kernel(
    const int* __restrict__ chars, const int* __restrict__ lens,
    const float* __restrict__ table, const float* __restrict__ Wt,
    const float* __restrict__ cb, float* __restrict__ word_emb)
{
  __shared__ float u[16][512];
  __shared__ float wt[8][1024];
  __shared__ int sidx[16];
  const int tid = threadIdx.x;
  const int ch = tid;
  const int w0 = blockIdx.x * 16;
  if (tid < 16) { int l = lens[w0 + tid]; sidx[tid] = (l < 1 ? 1 : l) - 1; }
  float c[16], acc0[16], acc1[16], acc2[16], acc3[16];
  #pragma unroll
  for (int w = 0; w < 16; ++w) { u[w][256 + ch] = 0.f; c[w] = 0.f; }
  const float cb0 = cb[ch], cb1 = cb[256 + ch], cb2 = cb[512 + ch], cb3 = cb[768 + ch];

  for (int t = 0; t < 16; ++t) {
    for (int w = 0; w < 16; ++w) {
      int cid = chars[(w0 + w) * 16 + t];
      u[w][ch] = table[(size_t)cid * 256 + ch];
    }
    #pragma unroll
    for (int w = 0; w < 16; ++w) { acc0[w] = cb0; acc1[w] = cb1; acc2[w] = cb2; acc3[w] = cb3; }
    for (int k0 = 0; k0 < 512; k0 += 8) {
      #pragma unroll
      for (int r = 0; r < 8; ++r)
        ((float4*)&wt[r][0])[tid] = ((const float4*)(Wt + (size_t)(k0 + r) * 1024))[tid];
      __syncthreads();
      #pragma unroll
      for (int kk = 0; kk < 8; ++kk) {
        const float wv0 = wt[kk][ch], wv1 = wt[kk][256 + ch];
        const float wv2 = wt[kk][512 + ch], wv3 = wt[kk][768 + ch];
        #pragma unroll
        for (int w = 0; w < 16; ++w) {
          const float uv = u[w][k0 + kk];
          acc0[w] = fmaf(wv0, uv, acc0[w]);
          acc1[w] = fmaf(wv1, uv, acc1[w]);
          acc2[w] = fmaf(wv2, uv, acc2[w]);
          acc3[w] = fmaf(wv3, uv, acc3[w]);
        }
      }
      __syncthreads();
    }
    #pragma unroll
    for (int w = 0; w < 16; ++w) {
      float iv = sigf(acc0[w]), fv = sigf(acc1[w]);
      float gv = tanhf(acc2[w]), ov = sigf(acc3[w]);
      c[w] = fv * c[w] + iv * gv;
      float h = ov * tanhf(c[w]);
      u[w][256 + ch] = h;
      if (t == sidx[w]) word_emb[(size_t)(w0 + w) * 256 + ch] = h;
    }
  }
}

// ---------------- generic fp32 GEMM: C = act(A @ B^T + bias)
// PERM=1: write col n at permuted position (n&511)*4 + (n>>9)  (unit-major x).
template <int SPLIT, int ACT, int PERM>
__global__ __launch_bounds__(256) void gemm_kernel(
    const float* __restrict__ A, const float* __restrict__ A2,
    const float* __restrict__ B, const float* __restrict__ bias,
    float* __restrict__ C, int M, int N, int K)
{
  __shared__ float At[8][132];
  __shared__ float Bt[8][132];
  const int tid = threadIdx.x;
  const int bm0 = blockIdx.x * 128, bn0 = blockIdx.y * 128;
  float acc[8][8];
  #pragma unroll
  for (int i = 0; i < 8; ++i)
    #pragma unroll
    for (int j = 0; j < 8; ++j) acc[i][j] = 0.f;
  const int sr = tid >> 1;
  const int sk = (tid & 1) * 4;
  const int tm = (tid >> 4) * 8, tn = (tid & 15) * 8;
  for (int k0 = 0; k0 < K; k0 += 8) {
    const int kg = k0 + sk;
    float4 av;
    if (SPLIT) {
      const float* srcp = (kg < 512) ? A : A2;
      av = *(const float4*)(srcp + (size_t)(bm0 + sr) * 512 + (kg & 511));
    } else {
      av = *(const float4*)(A + (size_t)(bm0 + sr) * K + kg);
    }
    float4 bv = {0.f, 0.f, 0.f, 0.f};
    if (bn0 + sr < N) bv = *(const float4*)(B + (size_t)(bn0 + sr) * K + kg);
    At[sk + 0][sr] = av.x; At[sk + 1][sr] = av.y; At[sk + 2][sr] = av.z; At[sk + 3][sr] = av.w;
    Bt[sk + 0][sr] = bv.x; Bt[sk + 1][sr] = bv.y; Bt[sk + 2][sr] = bv.z; Bt[sk + 3][sr] = bv.w;
    __syncthreads();
    #pragma unroll
    for (int kk = 0; kk < 8; ++kk) {
      float a[8], b[8];
      *(float4*)&a[0] = *(const float4*)&At[kk][tm];
      *(float4*)&a[4] = *(const float4*)&At[kk][tm + 4];
      *(float4*)&b[0] = *(const float4*)&Bt[kk][tn];
      *(float4*)&b[4] = *(const float4*)&Bt[kk][tn + 4];
      #pragma unroll
      for (int i = 0; i < 8; ++i)
        #pragma unroll
        for (int j = 0; j < 8; ++j) acc[i][j] = fmaf(a[i], b[j], acc[i][j]);
    }
    __syncthreads();
  }
  #pragma unroll
  for (int i = 0; i < 8; ++i) {
    const int m = bm0 + tm + i;
    float* crow = C + (size_t)m * N;
    #pragma unroll
    for (int j = 0; j < 8; ++j) {
      const int n = bn0 + tn + j;
      if (n < N) {
        float v = acc[i][j] + bias[n];
        if (ACT) v = tanhf(v);
        if (PERM) crow[((n & 511) << 2) | (n >> 9)] = v;
        else      crow[n] = v;
      }
    }
  }
}

// ---------------- persistent bidirectional scan v5 (1 wave / WG, no barriers)
// X is unit-major permuted: X[p*2048 + j*4 + g]  (g = i,f,g,o).
__global__ __launch_bounds__(64) void scan_kernel(
    const float* __restrict__ Xf, const float* __restrict__ Xb,
    const float* __restrict__ Whf, const float* __restrict__ Whb,
    unsigned long long* __restrict__ Tf, unsigned long long* __restrict__ Tb,
    float* __restrict__ Hf, float* __restrict__ Hb)
{
  const int bid = blockIdx.x;
  const int dir = bid >> 8;            // 256 WGs per dir
  const int wg  = bid & 255;
  const int lane = threadIdx.x;        // 0..63
  const int j0 = wg * 2;               // two hidden units per WG
  const float* X = dir ? Xb : Xf;
  const float* Wh = dir ? Whb : Whf;
  unsigned long long* T = dir ? Tb : Tf;
  float* Hd = dir ? Hb : Hf;

  // weights: w[u][g][i], k-slice = lane*8 + i
  float w[2][4][8];
  #pragma unroll
  for (int u = 0; u < 2; ++u)
    #pragma unroll
    for (int g = 0; g < 4; ++g) {
      const float* wr = Wh + ((size_t)(g * 512 + j0 + u)) * 512 + lane * 8;
      *(float4*)&w[u][g][0] = *(const float4*)wr;
      *(float4*)&w[u][g][4] = *(const float4*)(wr + 4);
    }

  float4 xc = {0,0,0,0}, xn = {0,0,0,0};
  if (lane < 2) {
    xc = *(const float4*)&X[(size_t)(dir ? NPOS - 1 : 0) * GDIM + (j0 + lane) * 4];
    xn = *(const float4*)&X[(size_t)(dir ? NPOS - 2 : 1) * GDIM + (j0 + lane) * 4];
  }
  float creg = 0.f;

  for (int s = 0; s < NPOS; ++s) {
    const int p = dir ? (NPOS - 1 - s) : s;
    float s00 = 0.f, s01 = 0.f, s02 = 0.f, s03 = 0.f;
    float s10 = 0.f, s11 = 0.f, s12 = 0.f, s13 = 0.f;

    if (s > 0) {
      const unsigned int tg = (unsigned int)s;
      const unsigned long long* bp = T + (size_t)((s - 1) & 1) * 512 + lane * 8;
      unsigned long long v0, v1, v2, v3, v4, v5, v6, v7;
      for (;;) {
        v0 = __hip_atomic_load(bp + 0, __ATOMIC_RELAXED, __HIP_MEMORY_SCOPE_AGENT);
        v1 = __hip_atomic_load(bp + 1, __ATOMIC_RELAXED, __HIP_MEMORY_SCOPE_AGENT);
        v2 = __hip_atomic_load(bp + 2, __ATOMIC_RELAXED, __HIP_MEMORY_SCOPE_AGENT);
        v3 = __hip_atomic_load(bp + 3, __ATOMIC_RELAXED, __HIP_MEMORY_SCOPE_AGENT);
        v4 = __hip_atomic_load(bp + 4, __ATOMIC_RELAXED, __HIP_MEMORY_SCOPE_AGENT);
        v5 = __hip_atomic_load(bp + 5, __ATOMIC_RELAXED, __HIP_MEMORY_SCOPE_AGENT);
        v6 = __hip_atomic_load(bp + 6, __ATOMIC_RELAXED, __HIP_MEMORY_SCOPE_AGENT);
        v7 = __hip_atomic_load(bp + 7, __ATOMIC_RELAXED, __HIP_MEMORY_SCOPE_AGENT);
        bool ok = ((unsigned int)(v0 >> 32) == tg) & ((unsigned int)(v1 >> 32) == tg)
                & ((unsigned int)(v2 >> 32) == tg) & ((unsigned int)(v3 >> 32) == tg)
                & ((unsigned int)(v4 >> 32) == tg) & ((unsigned int)(v5 >> 32) == tg)
                & ((unsigned int)(v6 >> 32) == tg) & ((unsigned int)(v7 >> 32) == tg);
        if (ok) break;
        __builtin_amdgcn_s_sleep(2);   // ~128 cy backoff: keep fabric clear for stores
      }
      float hk[8];
      hk[0] = __uint_as_float((unsigned int)v0);
      hk[1] = __uint_as_float((unsigned int)v1);
      hk[2] = __uint_as_float((unsigned int)v2);
      hk[3] = __uint_as_float((unsigned int)v3);
      hk[4] = __uint_as_float((unsigned int)v4);
      hk[5] = __uint_as_float((unsigned int)v5);
      hk[6] = __uint_as_float((unsigned int)v6);
      hk[7] = __uint_as_float((unsigned int)v7);
      #pragma unroll
      for (int i = 0; i < 8; ++i) {
        const float hv = hk[i];
        s00 = fmaf(w[0][0][i], hv, s00);
        s01 = fmaf(w[0][1][i], hv, s01);
        s02 = fmaf(w[0][2][i], hv, s02);
        s03 = fmaf(w[0][3][i], hv, s03);
        s10 = fmaf(w[1][0][i], hv, s10);
        s11 = fmaf(w[1][1][i], hv, s11);
        s12 = fmaf(w[1][2][i], hv, s12);
        s13 = fmaf(w[1][3][i], hv, s13);
      }
    }

    // issue x prefetch for step s+2 early (returns under reduce/nonlin)
    float4 xnn = {0, 0, 0, 0};
    if (lane < 2 && s + 2 < NPOS) {
      const int p2 = dir ? (NPOS - 3 - s) : (s + 2);
      xnn = *(const float4*)&X[(size_t)p2 * GDIM + (j0 + lane) * 4];
    }

    // wave butterfly: all lanes end with full sums
    #pragma unroll
    for (int m = 1; m < 64; m <<= 1) {
      s00 += __shfl_xor(s00, m); s01 += __shfl_xor(s01, m);
      s02 += __shfl_xor(s02, m); s03 += __shfl_xor(s03, m);
      s10 += __shfl_xor(s10, m); s11 += __shfl_xor(s11, m);
      s12 += __shfl_xor(s12, m); s13 += __shfl_xor(s13, m);
    }

    if (lane < 2) {
      const float gi = (lane ? s10 : s00) + xc.x;
      const float gf = (lane ? s11 : s01) + xc.y;
      const float gc = (lane ? s12 : s02) + xc.z;
      const float go = (lane ? s13 : s03) + xc.w;
      const float iv = sigf(gi), fv = sigf(gf);
      const float gv = tanh_fast(gc), ov = sigf(go);
      creg = fv * creg + iv * gv;
      const float h = ov * tanh_fast(creg);
      const int j = j0 + lane;
      unsigned long long pack = ((unsigned long long)(unsigned int)(s + 1) << 32)
                              | (unsigned long long)__float_as_uint(h);
      __hip_atomic_store(&T[(size_t)(s & 1) * 512 + j], pack,
                         __ATOMIC_RELAXED, __HIP_MEMORY_SCOPE_AGENT);
      Hd[(size_t)p * 512 + j] = h;
      xc = xn; xn = xnn;
    }
  }
}

extern "C" void kernel_launch(void* const* d_in, const int* in_sizes, int n_in,
                              void* d_out, int out_size, void* d_ws, size_t ws_size,
                              hipStream_t stream) {
  const int* chars = (const int*)d_in[0];
  const int* lens = (const int*)d_in[1];
  const float* table = (const float*)d_in[2];
  const float* cWih = (const float*)d_in[3];
  const float* cWhh = (const float*)d_in[4];
  const float* cb = (const float*)d_in[5];
  const float* Wih0 = (const float*)d_in[6];   // [2][2048][256]
  const float* Whh0 = (const float*)d_in[7];   // [2][2048][512]
  const float* b0 = (const float*)d_in[8];
  const float* Wih1 = (const float*)d_in[9];   // [2][2048][1024]
  const float* Whh1 = (const float*)d_in[10];  // [2][2048][512]
  const float* b1 = (const float*)d_in[11];
  const float* fc1w = (const float*)d_in[12];
  const float* fc1b = (const float*)d_in[13];
  const float* fc2w = (const float*)d_in[14];
  const float* fc2b = (const float*)d_in[15];
  float* out = (float*)d_out;

  char* ws = (char*)d_ws;
  size_t off = 0;
  auto alloc = [&](size_t bytes) -> void* {
    void* p = ws + off;
    off += (bytes + 255) & ~(size_t)255;
    return p;
  };
  float* word_emb = (float*)alloc((size_t)4096 * 256 * 4);
  float* X0f = (float*)alloc((size_t)4096 * 2048 * 4);
  float* X0b = (float*)alloc((size_t)4096 * 2048 * 4);
  float* H0f = (float*)alloc((size_t)4096 * 512 * 4);
  float* H0b = (float*)alloc((size_t)4096 * 512 * 4);
  float* H1f = (float*)alloc((size_t)4096 * 512 * 4);
  float* H1b = (float*)alloc((size_t)4096 * 512 * 4);
  float* fc1out = (float*)alloc((size_t)4096 * 512 * 4);
  float* Wt = (float*)alloc((size_t)512 * 1024 * 4);
  unsigned long long* Tall = (unsigned long long*)alloc((size_t)4 * 1024 * 8);  // 4 rings x 2 slots x 512
  unsigned long long* T0f = Tall;
  unsigned long long* T0b = Tall + 1024;
  unsigned long long* T1f = Tall + 2048;
  unsigned long long* T1b = Tall + 3072;
  if (off > ws_size) return;

  // clear tag rings (inside graph -> every replay re-synchronizes honestly)
  hipMemsetAsync(Tall, 0, (size_t)4 * 1024 * 8, stream);

  build_wt_kernel<<<dim3(8, 16), 256, 0, stream>>>(cWih, cWhh, Wt);
  char_lstm_kernel<<<256, 256, 0, stream>>>(chars, lens, table, Wt, cb, word_emb);

  gemm_kernel<0, 0, 1><<<dim3(32, 16), 256, 0, stream>>>(
      word_emb, nullptr, Wih0, b0, X0f, 4096, 2048, 256);
  gemm_kernel<0, 0, 1><<<dim3(32, 16), 256, 0, stream>>>(
      word_emb, nullptr, Wih0 + (size_t)2048 * 256, b0 + 2048, X0b, 4096, 2048, 256);
  scan_kernel<<<512, 64, 0, stream>>>(X0f, X0b, Whh0, Whh0 + (size_t)2048 * 512,
                                      T0f, T0b, H0f, H0b);

  gemm_kernel<1, 0, 1><<<dim3(32, 16), 256, 0, stream>>>(
      H0f, H0b, Wih1, b1, X0f, 4096, 2048, 1024);
  gemm_kernel<1, 0, 1><<<dim3(32, 16), 256, 0, stream>>>(
      H0f, H0b, Wih1 + (size_t)2048 * 1024, b1 + 2048, X0b, 4096, 2048, 1024);
  scan_kernel<<<512, 64, 0, stream>>>(X0f, X0b, Whh1, Whh1 + (size_t)2048 * 512,
                                      T1f, T1b, H1f, H1b);

  gemm_kernel<1, 1, 0><<<dim3(32, 4), 256, 0, stream>>>(
      H1f, H1b, fc1w, fc1b, fc1out, 4096, 512, 1024);
  gemm_kernel<0, 0, 0><<<dim3(32, 1), 256, 0, stream>>>(
      fc1out, nullptr, fc2w, fc2b, out, 4096, 50, 512);
}

// Round 6
// 16523.166 us; speedup vs baseline: 2.4974x; 2.4974x over previous
//
#include <hip/hip_runtime.h>
#include <math.h>
#include <stdint.h>

// BiLSTMModel: char-LSTM (GEMM-shaped) -> 2x BiLSTM scans (latency-bound) -> FCs.
// Scan v6 = round-3 skeleton (512-thr WG, one tagged word per thread, plain
// relaxed agent atomic polls, LDS broadcast, one barrier/step) +
//   (a) 4x-replicated 2-slot ring (poll-line contention / 4)
//   (b) unit-major permuted X (coalesced per-step x loads)
// GEMMs: PERM'd output + LDS swizzle (kills 4-way stride-8 read conflicts).

#define NPOS 4096
#define GDIM 2048   // 4*H

__device__ __forceinline__ float sigf(float x) { return 1.0f / (1.0f + __expf(-x)); }
__device__ __forceinline__ float tanh_fast(float x) {
  float e = __expf(2.f * x);
  return 1.f - 2.f / (e + 1.f);   // exact at +-inf, NaN-free
}

// ---------------- build transposed concat char weight: Wt[k][g]
__global__ __launch_bounds__(256) void build_wt_kernel(
    const float* __restrict__ cWih, const float* __restrict__ cWhh,
    float* __restrict__ Wt)
{
  __shared__ float tile[64][65];
  const int k0 = blockIdx.x * 64;
  const int g0 = blockIdx.y * 64;
  const float* src = (k0 < 256) ? cWih : cWhh;
  const int sk0 = k0 & 255;
  for (int i = threadIdx.x; i < 64 * 64; i += 256) {
    int r = i >> 6, cc = i & 63;
    tile[r][cc] = src[(size_t)(g0 + r) * 256 + sk0 + cc];
  }
  __syncthreads();
  for (int i = threadIdx.x; i < 64 * 64; i += 256) {
    int kk = i >> 6, gg = i & 63;
    Wt[(size_t)(k0 + kk) * 1024 + g0 + gg] = tile[gg][kk];
  }
}

// ---------------- char LSTM: 256 blocks x 16 words, thread = channel
__global__ __launch_bounds__(256) void char_lstm_kernel(
    const int* __restrict__ chars, const int* __restrict__ lens,
    const float* __restrict__ table, const float* __restrict__ Wt,
    const float* __restrict__ cb, float* __restrict__ word_emb)
{
  __shared__ float u[16][512];
  __shared__ float wt[8][1024];
  __shared__ int sidx[16];
  const int tid = threadIdx.x;
  const int ch = tid;
  const int w0 = blockIdx.x * 16;
  if (tid < 16) { int l = lens[w0 + tid]; sidx[tid] = (l < 1 ? 1 : l) - 1; }
  float c[16], acc0[16], acc1[16], acc2[16], acc3[16];
  #pragma unroll
  for (int w = 0; w < 16; ++w) { u[w][256 + ch] = 0.f; c[w] = 0.f; }
  const float cb0 = cb[ch], cb1 = cb[256 + ch], cb2 = cb[512 + ch], cb3 = cb[768 + ch];

  for (int t = 0; t < 16; ++t) {
    for (int w = 0; w < 16; ++w) {
      int cid = chars[(w0 + w) * 16 + t];
      u[w][ch] = table[(size_t)cid * 256 + ch];
    }
    #pragma unroll
    for (int w = 0; w < 16; ++w) { acc0[w] = cb0; acc1[w] = cb1; acc2[w] = cb2; acc3[w] = cb3; }
    for (int k0 = 0; k0 < 512; k0 += 8) {
      #pragma unroll
      for (int r = 0; r < 8; ++r)
        ((float4*)&wt[r][0])[tid] = ((const float4*)(Wt + (size_t)(k0 + r) * 1024))[tid];
      __syncthreads();
      #pragma unroll
      for (int kk = 0; kk < 8; ++kk) {
        const float wv0 = wt[kk][ch], wv1 = wt[kk][256 + ch];
        const float wv2 = wt[kk][512 + ch], wv3 = wt[kk][768 + ch];
        #pragma unroll
        for (int w = 0; w < 16; ++w) {
          const float uv = u[w][k0 + kk];
          acc0[w] = fmaf(wv0, uv, acc0[w]);
          acc1[w] = fmaf(wv1, uv, acc1[w]);
          acc2[w] = fmaf(wv2, uv, acc2[w]);
          acc3[w] = fmaf(wv3, uv, acc3[w]);
        }
      }
      __syncthreads();
    }
    #pragma unroll
    for (int w = 0; w < 16; ++w) {
      float iv = sigf(acc0[w]), fv = sigf(acc1[w]);
      float gv = tanhf(acc2[w]), ov = sigf(acc3[w]);
      c[w] = fv * c[w] + iv * gv;
      float h = ov * tanhf(c[w]);
      u[w][256 + ch] = h;
      if (t == sidx[w]) word_emb[(size_t)(w0 + w) * 256 + ch] = h;
    }
  }
}

// ---------------- generic fp32 GEMM: C = act(A @ B^T + bias)
// PERM=1: write col n at permuted position (n&511)*4 + (n>>9)  (unit-major x).
// LDS columns swizzled: col c at c + 4*(c>>3) (16B-aligned groups, ~2-way max).
#define SW(c) ((c) + (((c) >> 3) << 2))
template <int SPLIT, int ACT, int PERM>
__global__ __launch_bounds__(256) void gemm_kernel(
    const float* __restrict__ A, const float* __restrict__ A2,
    const float* __restrict__ B, const float* __restrict__ bias,
    float* __restrict__ C, int M, int N, int K)
{
  __shared__ float At[8 * 192];
  __shared__ float Bt[8 * 192];
  const int tid = threadIdx.x;
  const int bm0 = blockIdx.x * 128, bn0 = blockIdx.y * 128;
  float acc[8][8];
  #pragma unroll
  for (int i = 0; i < 8; ++i)
    #pragma unroll
    for (int j = 0; j < 8; ++j) acc[i][j] = 0.f;
  const int sr = tid >> 1;
  const int sk = (tid & 1) * 4;
  const int tm = (tid >> 4) * 8, tn = (tid & 15) * 8;
  const int swsr = SW(sr);
  const int stm = SW(tm), stn = SW(tn);
  for (int k0 = 0; k0 < K; k0 += 8) {
    const int kg = k0 + sk;
    float4 av;
    if (SPLIT) {
      const float* srcp = (kg < 512) ? A : A2;
      av = *(const float4*)(srcp + (size_t)(bm0 + sr) * 512 + (kg & 511));
    } else {
      av = *(const float4*)(A + (size_t)(bm0 + sr) * K + kg);
    }
    float4 bv = {0.f, 0.f, 0.f, 0.f};
    if (bn0 + sr < N) bv = *(const float4*)(B + (size_t)(bn0 + sr) * K + kg);
    At[(sk + 0) * 192 + swsr] = av.x; At[(sk + 1) * 192 + swsr] = av.y;
    At[(sk + 2) * 192 + swsr] = av.z; At[(sk + 3) * 192 + swsr] = av.w;
    Bt[(sk + 0) * 192 + swsr] = bv.x; Bt[(sk + 1) * 192 + swsr] = bv.y;
    Bt[(sk + 2) * 192 + swsr] = bv.z; Bt[(sk + 3) * 192 + swsr] = bv.w;
    __syncthreads();
    #pragma unroll
    for (int kk = 0; kk < 8; ++kk) {
      float a[8], b[8];
      *(float4*)&a[0] = *(const float4*)&At[kk * 192 + stm];
      *(float4*)&a[4] = *(const float4*)&At[kk * 192 + stm + 4];
      *(float4*)&b[0] = *(const float4*)&Bt[kk * 192 + stn];
      *(float4*)&b[4] = *(const float4*)&Bt[kk * 192 + stn + 4];
      #pragma unroll
      for (int i = 0; i < 8; ++i)
        #pragma unroll
        for (int j = 0; j < 8; ++j) acc[i][j] = fmaf(a[i], b[j], acc[i][j]);
    }
    __syncthreads();
  }
  #pragma unroll
  for (int i = 0; i < 8; ++i) {
    const int m = bm0 + tm + i;
    float* crow = C + (size_t)m * N;
    #pragma unroll
    for (int j = 0; j < 8; ++j) {
      const int n = bn0 + tn + j;
      if (n < N) {
        float v = acc[i][j] + bias[n];
        if (ACT) v = tanhf(v);
        if (PERM) crow[((n & 511) << 2) | (n >> 9)] = v;
        else      crow[n] = v;
      }
    }
  }
}

// ---------------- persistent bidirectional scan v6 (round-3 skeleton)
// grid = 64 blocks x 512 thr: dir = bid&1, wg = bid>>1 (16 hidden units/WG).
// row8 = tid>>3 = u*4+g, klane = tid&7 (64-wide k chunk per thread).
// Ring: 4 replicas x 2 slots x 512 tagged words. Producer leaders store to all
// 4 replicas; consumer WG polls replica wg&3, one word per thread.
// X is unit-major permuted: X[p*2048 + j*4 + g] -> WG slice = 64 consecutive.
__global__ __launch_bounds__(512) void scan_kernel(
    const float* __restrict__ Xf, const float* __restrict__ Xb,
    const float* __restrict__ Whf, const float* __restrict__ Whb,
    unsigned long long* __restrict__ Tf, unsigned long long* __restrict__ Tb,
    float* __restrict__ Hf, float* __restrict__ Hb)
{
  __shared__ float lds_h[2][576];   // logical j at j + (j>>5)*4
  const int tid = threadIdx.x;
  const int dir = blockIdx.x & 1;
  const int wg  = blockIdx.x >> 1;
  const float* X = dir ? Xb : Xf;
  const float* Wh = dir ? Whb : Whf;
  unsigned long long* T = dir ? Tb : Tf;
  float* Hd = dir ? Hb : Hf;

  const int row8 = tid >> 3;              // 0..63
  const int klane = tid & 7;
  const int u = row8 >> 2, g = row8 & 3;
  const int R = g * 512 + wg * 16 + u;    // gate-major row in [0,2048)

  float wreg[64];
  {
    const float* wrow = Wh + (size_t)R * 512 + klane * 64;
    #pragma unroll
    for (int i = 0; i < 16; ++i) {
      float4 v = ((const float4*)wrow)[i];
      wreg[4 * i] = v.x; wreg[4 * i + 1] = v.y; wreg[4 * i + 2] = v.z; wreg[4 * i + 3] = v.w;
    }
  }
  const int l0 = 72 * klane;       // padded base of logical [klane*64, +32)
  const int l1 = l0 + 36;          // padded base of logical [klane*64+32, +32)
  const int la = tid + ((tid >> 5) << 2);   // padded slot of logical word tid
  const int rep = wg & 3;                   // replica this WG polls

  for (int i = tid; i < 576; i += 512) lds_h[0][i] = 0.f;

  // x loads: permuted X -> WG slice is 64 consecutive floats [wg*64 .. +64)
  const bool xl = (klane == 0);
  const int xoff = wg * 64 + row8;
  float xcur = 0.f, xnxt = 0.f;
  if (xl) {
    xcur = X[(size_t)(dir ? NPOS - 1 : 0) * GDIM + xoff];
    xnxt = X[(size_t)(dir ? NPOS - 2 : 1) * GDIM + xoff];
  }
  float creg = 0.f;
  __syncthreads();

  for (int s = 0; s < NPOS; ++s) {
    const int p = dir ? (NPOS - 1 - s) : s;
    if (s > 0) {
      const unsigned int tg = (unsigned int)s;
      const unsigned long long* w =
          T + (size_t)((rep << 1) | ((s - 1) & 1)) * 512 + tid;
      unsigned long long v;
      do { v = __hip_atomic_load(w, __ATOMIC_RELAXED, __HIP_MEMORY_SCOPE_AGENT); }
      while ((unsigned int)(v >> 32) != tg);
      lds_h[s & 1][la] = __uint_as_float((unsigned int)v);
    }
    __syncthreads();
    const float* hb = &lds_h[s & 1][0];
    float sum = xl ? xcur : 0.f;
    if (xl) {   // shift x pipeline; load for step s+2 (consumed in ~2 steps)
      xcur = xnxt;
      if (s + 2 < NPOS) xnxt = X[(size_t)(dir ? NPOS - 3 - s : s + 2) * GDIM + xoff];
    }
    #pragma unroll
    for (int i = 0; i < 8; ++i) {
      float4 a = *(const float4*)&hb[l0 + 4 * i];
      sum = fmaf(wreg[4 * i + 0], a.x, sum);
      sum = fmaf(wreg[4 * i + 1], a.y, sum);
      sum = fmaf(wreg[4 * i + 2], a.z, sum);
      sum = fmaf(wreg[4 * i + 3], a.w, sum);
    }
    #pragma unroll
    for (int i = 0; i < 8; ++i) {
      float4 a = *(const float4*)&hb[l1 + 4 * i];
      sum = fmaf(wreg[32 + 4 * i + 0], a.x, sum);
      sum = fmaf(wreg[32 + 4 * i + 1], a.y, sum);
      sum = fmaf(wreg[32 + 4 * i + 2], a.z, sum);
      sum = fmaf(wreg[32 + 4 * i + 3], a.w, sum);
    }
    sum += __shfl_xor(sum, 1);
    sum += __shfl_xor(sum, 2);
    sum += __shfl_xor(sum, 4);
    const int base = (tid & 63) & ~31;   // this unit's lane base within the wave
    float gf = __shfl(sum, base + 8);
    float gg = __shfl(sum, base + 16);
    float go = __shfl(sum, base + 24);
    if ((tid & 31) == 0) {               // leader: holds i-gate in sum
      float iv = sigf(sum), fv = sigf(gf), gv = tanh_fast(gg), ov = sigf(go);
      creg = fv * creg + iv * gv;
      float h = ov * tanh_fast(creg);
      const int j = wg * 16 + u;
      unsigned long long pack = ((unsigned long long)(unsigned int)(s + 1) << 32)
                              | (unsigned long long)__float_as_uint(h);
      #pragma unroll
      for (int r2 = 0; r2 < 4; ++r2)
        __hip_atomic_store(&T[(size_t)((r2 << 1) | (s & 1)) * 512 + j], pack,
                           __ATOMIC_RELAXED, __HIP_MEMORY_SCOPE_AGENT);
      Hd[(size_t)p * 512 + j] = h;
    }
  }
}

extern "C" void kernel_launch(void* const* d_in, const int* in_sizes, int n_in,
                              void* d_out, int out_size, void* d_ws, size_t ws_size,
                              hipStream_t stream) {
  const int* chars = (const int*)d_in[0];
  const int* lens = (const int*)d_in[1];
  const float* table = (const float*)d_in[2];
  const float* cWih = (const float*)d_in[3];
  const float* cWhh = (const float*)d_in[4];
  const float* cb = (const float*)d_in[5];
  const float* Wih0 = (const float*)d_in[6];   // [2][2048][256]
  const float* Whh0 = (const float*)d_in[7];   // [2][2048][512]
  const float* b0 = (const float*)d_in[8];
  const float* Wih1 = (const float*)d_in[9];   // [2][2048][1024]
  const float* Whh1 = (const float*)d_in[10];  // [2][2048][512]
  const float* b1 = (const float*)d_in[11];
  const float* fc1w = (const float*)d_in[12];
  const float* fc1b = (const float*)d_in[13];
  const float* fc2w = (const float*)d_in[14];
  const float* fc2b = (const float*)d_in[15];
  float* out = (float*)d_out;

  char* ws = (char*)d_ws;
  size_t off = 0;
  auto alloc = [&](size_t bytes) -> void* {
    void* p = ws + off;
    off += (bytes + 255) & ~(size_t)255;
    return p;
  };
  float* word_emb = (float*)alloc((size_t)4096 * 256 * 4);
  float* X0f = (float*)alloc((size_t)4096 * 2048 * 4);
  float* X0b = (float*)alloc((size_t)4096 * 2048 * 4);
  float* H0f = (float*)alloc((size_t)4096 * 512 * 4);
  float* H0b = (float*)alloc((size_t)4096 * 512 * 4);
  float* H1f = (float*)alloc((size_t)4096 * 512 * 4);
  float* H1b = (float*)alloc((size_t)4096 * 512 * 4);
  float* fc1out = (float*)alloc((size_t)4096 * 512 * 4);
  float* Wt = (float*)alloc((size_t)512 * 1024 * 4);
  // 4 rings x (4 replicas x 2 slots x 512 words) x 8B = 512 KB
  unsigned long long* Tall = (unsigned long long*)alloc((size_t)4 * 4096 * 8);
  unsigned long long* T0f = Tall;
  unsigned long long* T0b = Tall + 4096;
  unsigned long long* T1f = Tall + 8192;
  unsigned long long* T1b = Tall + 12288;
  if (off > ws_size) return;

  // clear tag rings (inside graph -> every replay re-synchronizes honestly)
  hipMemsetAsync(Tall, 0, (size_t)4 * 4096 * 8, stream);

  build_wt_kernel<<<dim3(8, 16), 256, 0, stream>>>(cWih, cWhh, Wt);
  char_lstm_kernel<<<256, 256, 0, stream>>>(chars, lens, table, Wt, cb, word_emb);

  gemm_kernel<0, 0, 1><<<dim3(32, 16), 256, 0, stream>>>(
      word_emb, nullptr, Wih0, b0, X0f, 4096, 2048, 256);
  gemm_kernel<0, 0, 1><<<dim3(32, 16), 256, 0, stream>>>(
      word_emb, nullptr, Wih0 + (size_t)2048 * 256, b0 + 2048, X0b, 4096, 2048, 256);
  scan_kernel<<<64, 512, 0, stream>>>(X0f, X0b, Whh0, Whh0 + (size_t)2048 * 512,
                                      T0f, T0b, H0f, H0b);

  gemm_kernel<1, 0, 1><<<dim3(32, 16), 256, 0, stream>>>(
      H0f, H0b, Wih1, b1, X0f, 4096, 2048, 1024);
  gemm_kernel<1, 0, 1><<<dim3(32, 16), 256, 0, stream>>>(
      H0f, H0b, Wih1 + (size_t)2048 * 1024, b1 + 2048, X0b, 4096, 2048, 1024);
  scan_kernel<<<64, 512, 0, stream>>>(X0f, X0b, Whh1, Whh1 + (size_t)2048 * 512,
                                      T1f, T1b, H1f, H1b);

  gemm_kernel<1, 1, 0><<<dim3(32, 4), 256, 0, stream>>>(
      H1f, H1b, fc1w, fc1b, fc1out, 4096, 512, 1024);
  gemm_kernel<0, 0, 0><<<dim3(32, 1), 256, 0, stream>>>(
      fc1out, nullptr, fc2w, fc2b, out, 4096, 50, 512);
}

// Round 7
// 16057.610 us; speedup vs baseline: 2.5699x; 1.0290x over previous
//
#include <hip/hip_runtime.h>
#include <math.h>
#include <stdint.h>

// BiLSTMModel: char-LSTM (GEMM-shaped) -> 2x BiLSTM scans (latency-bound) -> FCs.
// Scan v7 = v6 skeleton (512-thr WG, one tagged word per thread, plain relaxed
// agent atomic polls, LDS broadcast, one barrier/step, 4x-replicated 2-slot
// ring, unit-major permuted X) + 4-way split FMA chains (critical-path cut).
// char-LSTM v2: 8 words/block, 512 blocks -> 2 blocks/CU, 8 waves/CU.

#define NPOS 4096
#define GDIM 2048   // 4*H

__device__ __forceinline__ float sigf(float x) { return 1.0f / (1.0f + __expf(-x)); }
__device__ __forceinline__ float tanh_fast(float x) {
  float e = __expf(2.f * x);
  return 1.f - 2.f / (e + 1.f);   // exact at +-inf, NaN-free
}

// ---------------- build transposed concat char weight: Wt[k][g]
__global__ __launch_bounds__(256) void build_wt_kernel(
    const float* __restrict__ cWih, const float* __restrict__ cWhh,
    float* __restrict__ Wt)
{
  __shared__ float tile[64][65];
  const int k0 = blockIdx.x * 64;
  const int g0 = blockIdx.y * 64;
  const float* src = (k0 < 256) ? cWih : cWhh;
  const int sk0 = k0 & 255;
  for (int i = threadIdx.x; i < 64 * 64; i += 256) {
    int r = i >> 6, cc = i & 63;
    tile[r][cc] = src[(size_t)(g0 + r) * 256 + sk0 + cc];
  }
  __syncthreads();
  for (int i = threadIdx.x; i < 64 * 64; i += 256) {
    int kk = i >> 6, gg = i & 63;
    Wt[(size_t)(k0 + kk) * 1024 + g0 + gg] = tile[gg][kk];
  }
}

// ---------------- char LSTM v2: 512 blocks x 8 words, thread = channel
__global__ __launch_bounds__(256) void char_lstm_kernel(
    const int* __restrict__ chars, const int* __restrict__ lens,
    const float* __restrict__ table, const float* __restrict__ Wt,
    const float* __restrict__ cb, float* __restrict__ word_emb)
{
  __shared__ float u[8][512];
  __shared__ float wt[8][1024];
  __shared__ int sidx[8];
  const int tid = threadIdx.x;
  const int ch = tid;
  const int w0 = blockIdx.x * 8;
  if (tid < 8) { int l = lens[w0 + tid]; sidx[tid] = (l < 1 ? 1 : l) - 1; }
  float c[8], acc0[8], acc1[8], acc2[8], acc3[8];
  #pragma unroll
  for (int w = 0; w < 8; ++w) { u[w][256 + ch] = 0.f; c[w] = 0.f; }
  const float cb0 = cb[ch], cb1 = cb[256 + ch], cb2 = cb[512 + ch], cb3 = cb[768 + ch];

  for (int t = 0; t < 16; ++t) {
    for (int w = 0; w < 8; ++w) {
      int cid = chars[(w0 + w) * 16 + t];
      u[w][ch] = table[(size_t)cid * 256 + ch];
    }
    #pragma unroll
    for (int w = 0; w < 8; ++w) { acc0[w] = cb0; acc1[w] = cb1; acc2[w] = cb2; acc3[w] = cb3; }
    for (int k0 = 0; k0 < 512; k0 += 8) {
      #pragma unroll
      for (int r = 0; r < 8; ++r)
        ((float4*)&wt[r][0])[tid] = ((const float4*)(Wt + (size_t)(k0 + r) * 1024))[tid];
      __syncthreads();
      #pragma unroll
      for (int kk = 0; kk < 8; ++kk) {
        const float wv0 = wt[kk][ch], wv1 = wt[kk][256 + ch];
        const float wv2 = wt[kk][512 + ch], wv3 = wt[kk][768 + ch];
        #pragma unroll
        for (int w = 0; w < 8; ++w) {
          const float uv = u[w][k0 + kk];
          acc0[w] = fmaf(wv0, uv, acc0[w]);
          acc1[w] = fmaf(wv1, uv, acc1[w]);
          acc2[w] = fmaf(wv2, uv, acc2[w]);
          acc3[w] = fmaf(wv3, uv, acc3[w]);
        }
      }
      __syncthreads();
    }
    #pragma unroll
    for (int w = 0; w < 8; ++w) {
      float iv = sigf(acc0[w]), fv = sigf(acc1[w]);
      float gv = tanhf(acc2[w]), ov = sigf(acc3[w]);
      c[w] = fv * c[w] + iv * gv;
      float h = ov * tanhf(c[w]);
      u[w][256 + ch] = h;
      if (t == sidx[w]) word_emb[(size_t)(w0 + w) * 256 + ch] = h;
    }
  }
}

// ---------------- generic fp32 GEMM: C = act(A @ B^T + bias)
// PERM=1: write col n at permuted position (n&511)*4 + (n>>9)  (unit-major x).
// LDS columns swizzled: col c at c + 4*(c>>3) (16B-aligned groups).
#define SW(c) ((c) + (((c) >> 3) << 2))
template <int SPLIT, int ACT, int PERM>
__global__ __launch_bounds__(256) void gemm_kernel(
    const float* __restrict__ A, const float* __restrict__ A2,
    const float* __restrict__ B, const float* __restrict__ bias,
    float* __restrict__ C, int M, int N, int K)
{
  __shared__ float At[8 * 192];
  __shared__ float Bt[8 * 192];
  const int tid = threadIdx.x;
  const int bm0 = blockIdx.x * 128, bn0 = blockIdx.y * 128;
  float acc[8][8];
  #pragma unroll
  for (int i = 0; i < 8; ++i)
    #pragma unroll
    for (int j = 0; j < 8; ++j) acc[i][j] = 0.f;
  const int sr = tid >> 1;
  const int sk = (tid & 1) * 4;
  const int tm = (tid >> 4) * 8, tn = (tid & 15) * 8;
  const int swsr = SW(sr);
  const int stm = SW(tm), stn = SW(tn);
  for (int k0 = 0; k0 < K; k0 += 8) {
    const int kg = k0 + sk;
    float4 av;
    if (SPLIT) {
      const float* srcp = (kg < 512) ? A : A2;
      av = *(const float4*)(srcp + (size_t)(bm0 + sr) * 512 + (kg & 511));
    } else {
      av = *(const float4*)(A + (size_t)(bm0 + sr) * K + kg);
    }
    float4 bv = {0.f, 0.f, 0.f, 0.f};
    if (bn0 + sr < N) bv = *(const float4*)(B + (size_t)(bn0 + sr) * K + kg);
    At[(sk + 0) * 192 + swsr] = av.x; At[(sk + 1) * 192 + swsr] = av.y;
    At[(sk + 2) * 192 + swsr] = av.z; At[(sk + 3) * 192 + swsr] = av.w;
    Bt[(sk + 0) * 192 + swsr] = bv.x; Bt[(sk + 1) * 192 + swsr] = bv.y;
    Bt[(sk + 2) * 192 + swsr] = bv.z; Bt[(sk + 3) * 192 + swsr] = bv.w;
    __syncthreads();
    #pragma unroll
    for (int kk = 0; kk < 8; ++kk) {
      float a[8], b[8];
      *(float4*)&a[0] = *(const float4*)&At[kk * 192 + stm];
      *(float4*)&a[4] = *(const float4*)&At[kk * 192 + stm + 4];
      *(float4*)&b[0] = *(const float4*)&Bt[kk * 192 + stn];
      *(float4*)&b[4] = *(const float4*)&Bt[kk * 192 + stn + 4];
      #pragma unroll
      for (int i = 0; i < 8; ++i)
        #pragma unroll
        for (int j = 0; j < 8; ++j) acc[i][j] = fmaf(a[i], b[j], acc[i][j]);
    }
    __syncthreads();
  }
  #pragma unroll
  for (int i = 0; i < 8; ++i) {
    const int m = bm0 + tm + i;
    float* crow = C + (size_t)m * N;
    #pragma unroll
    for (int j = 0; j < 8; ++j) {
      const int n = bn0 + tn + j;
      if (n < N) {
        float v = acc[i][j] + bias[n];
        if (ACT) v = tanhf(v);
        if (PERM) crow[((n & 511) << 2) | (n >> 9)] = v;
        else      crow[n] = v;
      }
    }
  }
}

// ---------------- persistent bidirectional scan v7
// grid = 64 blocks x 512 thr: dir = bid&1, wg = bid>>1 (16 hidden units/WG).
// row8 = tid>>3 = u*4+g, klane = tid&7 (64-wide k chunk per thread).
// Ring: 4 replicas x 2 slots x 512 tagged words; leaders store to all 4,
// consumer WG polls replica wg&3, one word per thread.
// Gate dot-product: 4 independent 16-FMA chains + tree (critical-path cut).
__global__ __launch_bounds__(512) void scan_kernel(
    const float* __restrict__ Xf, const float* __restrict__ Xb,
    const float* __restrict__ Whf, const float* __restrict__ Whb,
    unsigned long long* __restrict__ Tf, unsigned long long* __restrict__ Tb,
    float* __restrict__ Hf, float* __restrict__ Hb)
{
  __shared__ float lds_h[2][576];   // logical j at j + (j>>5)*4
  const int tid = threadIdx.x;
  const int dir = blockIdx.x & 1;
  const int wg  = blockIdx.x >> 1;
  const float* X = dir ? Xb : Xf;
  const float* Wh = dir ? Whb : Whf;
  unsigned long long* T = dir ? Tb : Tf;
  float* Hd = dir ? Hb : Hf;

  const int row8 = tid >> 3;              // 0..63
  const int klane = tid & 7;
  const int u = row8 >> 2, g = row8 & 3;
  const int R = g * 512 + wg * 16 + u;    // gate-major row in [0,2048)

  float wreg[64];
  {
    const float* wrow = Wh + (size_t)R * 512 + klane * 64;
    #pragma unroll
    for (int i = 0; i < 16; ++i) {
      float4 v = ((const float4*)wrow)[i];
      wreg[4 * i] = v.x; wreg[4 * i + 1] = v.y; wreg[4 * i + 2] = v.z; wreg[4 * i + 3] = v.w;
    }
  }
  const int l0 = 72 * klane;       // padded base of logical [klane*64, +32)
  const int l1 = l0 + 36;          // padded base of logical [klane*64+32, +32)
  const int la = tid + ((tid >> 5) << 2);   // padded slot of logical word tid
  const int rep = wg & 3;                   // replica this WG polls

  for (int i = tid; i < 576; i += 512) lds_h[0][i] = 0.f;

  // x loads: permuted X -> WG slice is 64 consecutive floats [wg*64 .. +64)
  const bool xl = (klane == 0);
  const int xoff = wg * 64 + row8;
  float xcur = 0.f, xnxt = 0.f;
  if (xl) {
    xcur = X[(size_t)(dir ? NPOS - 1 : 0) * GDIM + xoff];
    xnxt = X[(size_t)(dir ? NPOS - 2 : 1) * GDIM + xoff];
  }
  float creg = 0.f;
  __syncthreads();

  for (int s = 0; s < NPOS; ++s) {
    const int p = dir ? (NPOS - 1 - s) : s;
    if (s > 0) {
      const unsigned int tg = (unsigned int)s;
      const unsigned long long* w =
          T + (size_t)((rep << 1) | ((s - 1) & 1)) * 512 + tid;
      unsigned long long v;
      do { v = __hip_atomic_load(w, __ATOMIC_RELAXED, __HIP_MEMORY_SCOPE_AGENT); }
      while ((unsigned int)(v >> 32) != tg);
      lds_h[s & 1][la] = __uint_as_float((unsigned int)v);
    }
    __syncthreads();
    const float* hb = &lds_h[s & 1][0];
    float sA = xl ? xcur : 0.f, sB = 0.f, sC = 0.f, sD = 0.f;
    if (xl) {   // shift x pipeline; load for step s+2 (consumed 2 steps later)
      xcur = xnxt;
      if (s + 2 < NPOS) xnxt = X[(size_t)(dir ? NPOS - 3 - s : s + 2) * GDIM + xoff];
    }
    // 4 independent 16-FMA chains (was one 64-deep chain)
    #pragma unroll
    for (int i = 0; i < 4; ++i) {
      float4 a = *(const float4*)&hb[l0 + 4 * i];
      sA = fmaf(wreg[4 * i + 0], a.x, sA);
      sA = fmaf(wreg[4 * i + 1], a.y, sA);
      sA = fmaf(wreg[4 * i + 2], a.z, sA);
      sA = fmaf(wreg[4 * i + 3], a.w, sA);
      float4 b = *(const float4*)&hb[l0 + 16 + 4 * i];
      sB = fmaf(wreg[16 + 4 * i + 0], b.x, sB);
      sB = fmaf(wreg[16 + 4 * i + 1], b.y, sB);
      sB = fmaf(wreg[16 + 4 * i + 2], b.z, sB);
      sB = fmaf(wreg[16 + 4 * i + 3], b.w, sB);
      float4 c = *(const float4*)&hb[l1 + 4 * i];
      sC = fmaf(wreg[32 + 4 * i + 0], c.x, sC);
      sC = fmaf(wreg[32 + 4 * i + 1], c.y, sC);
      sC = fmaf(wreg[32 + 4 * i + 2], c.z, sC);
      sC = fmaf(wreg[32 + 4 * i + 3], c.w, sC);
      float4 d = *(const float4*)&hb[l1 + 16 + 4 * i];
      sD = fmaf(wreg[48 + 4 * i + 0], d.x, sD);
      sD = fmaf(wreg[48 + 4 * i + 1], d.y, sD);
      sD = fmaf(wreg[48 + 4 * i + 2], d.z, sD);
      sD = fmaf(wreg[48 + 4 * i + 3], d.w, sD);
    }
    float sum = (sA + sB) + (sC + sD);
    sum += __shfl_xor(sum, 1);
    sum += __shfl_xor(sum, 2);
    sum += __shfl_xor(sum, 4);
    const int base = (tid & 63) & ~31;   // this unit's lane base within the wave
    float gf = __shfl(sum, base + 8);
    float gg = __shfl(sum, base + 16);
    float go = __shfl(sum, base + 24);
    if ((tid & 31) == 0) {               // leader: holds i-gate in sum
      float iv = sigf(sum), fv = sigf(gf), gv = tanh_fast(gg), ov = sigf(go);
      creg = fv * creg + iv * gv;
      float h = ov * tanh_fast(creg);
      const int j = wg * 16 + u;
      unsigned long long pack = ((unsigned long long)(unsigned int)(s + 1) << 32)
                              | (unsigned long long)__float_as_uint(h);
      #pragma unroll
      for (int r2 = 0; r2 < 4; ++r2)
        __hip_atomic_store(&T[(size_t)((r2 << 1) | (s & 1)) * 512 + j], pack,
                           __ATOMIC_RELAXED, __HIP_MEMORY_SCOPE_AGENT);
      Hd[(size_t)p * 512 + j] = h;
    }
  }
}

extern "C" void kernel_launch(void* const* d_in, const int* in_sizes, int n_in,
                              void* d_out, int out_size, void* d_ws, size_t ws_size,
                              hipStream_t stream) {
  const int* chars = (const int*)d_in[0];
  const int* lens = (const int*)d_in[1];
  const float* table = (const float*)d_in[2];
  const float* cWih = (const float*)d_in[3];
  const float* cWhh = (const float*)d_in[4];
  const float* cb = (const float*)d_in[5];
  const float* Wih0 = (const float*)d_in[6];   // [2][2048][256]
  const float* Whh0 = (const float*)d_in[7];   // [2][2048][512]
  const float* b0 = (const float*)d_in[8];
  const float* Wih1 = (const float*)d_in[9];   // [2][2048][1024]
  const float* Whh1 = (const float*)d_in[10];  // [2][2048][512]
  const float* b1 = (const float*)d_in[11];
  const float* fc1w = (const float*)d_in[12];
  const float* fc1b = (const float*)d_in[13];
  const float* fc2w = (const float*)d_in[14];
  const float* fc2b = (const float*)d_in[15];
  float* out = (float*)d_out;

  char* ws = (char*)d_ws;
  size_t off = 0;
  auto alloc = [&](size_t bytes) -> void* {
    void* p = ws + off;
    off += (bytes + 255) & ~(size_t)255;
    return p;
  };
  float* word_emb = (float*)alloc((size_t)4096 * 256 * 4);
  float* X0f = (float*)alloc((size_t)4096 * 2048 * 4);
  float* X0b = (float*)alloc((size_t)4096 * 2048 * 4);
  float* H0f = (float*)alloc((size_t)4096 * 512 * 4);
  float* H0b = (float*)alloc((size_t)4096 * 512 * 4);
  float* H1f = (float*)alloc((size_t)4096 * 512 * 4);
  float* H1b = (float*)alloc((size_t)4096 * 512 * 4);
  float* fc1out = (float*)alloc((size_t)4096 * 512 * 4);
  float* Wt = (float*)alloc((size_t)512 * 1024 * 4);
  // 4 rings x (4 replicas x 2 slots x 512 words) x 8B = 512 KB
  unsigned long long* Tall = (unsigned long long*)alloc((size_t)4 * 4096 * 8);
  unsigned long long* T0f = Tall;
  unsigned long long* T0b = Tall + 4096;
  unsigned long long* T1f = Tall + 8192;
  unsigned long long* T1b = Tall + 12288;
  if (off > ws_size) return;

  // clear tag rings (inside graph -> every replay re-synchronizes honestly)
  hipMemsetAsync(Tall, 0, (size_t)4 * 4096 * 8, stream);

  build_wt_kernel<<<dim3(8, 16), 256, 0, stream>>>(cWih, cWhh, Wt);
  char_lstm_kernel<<<512, 256, 0, stream>>>(chars, lens, table, Wt, cb, word_emb);

  gemm_kernel<0, 0, 1><<<dim3(32, 16), 256, 0, stream>>>(
      word_emb, nullptr, Wih0, b0, X0f, 4096, 2048, 256);
  gemm_kernel<0, 0, 1><<<dim3(32, 16), 256, 0, stream>>>(
      word_emb, nullptr, Wih0 + (size_t)2048 * 256, b0 + 2048, X0b, 4096, 2048, 256);
  scan_kernel<<<64, 512, 0, stream>>>(X0f, X0b, Whh0, Whh0 + (size_t)2048 * 512,
                                      T0f, T0b, H0f, H0b);

  gemm_kernel<1, 0, 1><<<dim3(32, 16), 256, 0, stream>>>(
      H0f, H0b, Wih1, b1, X0f, 4096, 2048, 1024);
  gemm_kernel<1, 0, 1><<<dim3(32, 16), 256, 0, stream>>>(
      H0f, H0b, Wih1 + (size_t)2048 * 1024, b1 + 2048, X0b, 4096, 2048, 1024);
  scan_kernel<<<64, 512, 0, stream>>>(X0f, X0b, Whh1, Whh1 + (size_t)2048 * 512,
                                      T1f, T1b, H1f, H1b);

  gemm_kernel<1, 1, 0><<<dim3(32, 4), 256, 0, stream>>>(
      H1f, H1b, fc1w, fc1b, fc1out, 4096, 512, 1024);
  gemm_kernel<0, 0, 0><<<dim3(32, 1), 256, 0, stream>>>(
      fc1out, nullptr, fc2w, fc2b, out, 4096, 50, 512);
}